// Round 8
// baseline (471.775 us; speedup 1.0000x reference)
//
#include <hip/hip_runtime.h>

#define B_  4
#define S_  1024
#define D_  1024
#define H_  16
#define DH  64
#define BS  4096   // B_*S_

typedef __bf16 bf16x8 __attribute__((ext_vector_type(8)));
typedef float  f32x4  __attribute__((ext_vector_type(4)));

__device__ __forceinline__ unsigned short f2bf(float f) {
    __bf16 b = (__bf16)f;
    return __builtin_bit_cast(unsigned short, b);
}
__device__ __forceinline__ float bf2f(unsigned short u) {
    return (float)__builtin_bit_cast(__bf16, u);
}

// ---------------- fused prep: wTsplit(Wq), wTsplit(Wk), wTsplit(Wo, hi-only), wv_reduce ----------------
__global__ __launch_bounds__(256) void prep(const float* __restrict__ Wq,
                                            const float* __restrict__ Wk,
                                            const float* __restrict__ Wo,
                                            const float* __restrict__ Wv,
                                            const float* __restrict__ bv,
                                            unsigned short* __restrict__ WqTh,
                                            unsigned short* __restrict__ WqTl,
                                            unsigned short* __restrict__ WkTh,
                                            unsigned short* __restrict__ WkTl,
                                            unsigned short* __restrict__ WoTh,
                                            float* __restrict__ Wvsh,
                                            float* __restrict__ bvsh) {
    __shared__ float tile[32][33];
    int bid = blockIdx.x, tid = threadIdx.x;
    if (bid < 3072) {
        const float* W;
        unsigned short *Th, *Tl;
        int wantLo;
        if (bid < 1024)      { W = Wq; Th = WqTh; Tl = WqTl; wantLo = 1; }
        else if (bid < 2048) { W = Wk; Th = WkTh; Tl = WkTl; wantLo = 1; bid -= 1024; }
        else                 { W = Wo; Th = WoTh; Tl = nullptr; wantLo = 0; bid -= 2048; }
        int tn = bid & 31, tk = bid >> 5;
        int r = tid >> 3, c4 = (tid & 7) * 4;
        float4 v = *(const float4*)(W + (size_t)(tk * 32 + r) * D_ + tn * 32 + c4);
        tile[r][c4 + 0] = v.x;
        tile[r][c4 + 1] = v.y;
        tile[r][c4 + 2] = v.z;
        tile[r][c4 + 3] = v.w;
        __syncthreads();
        unsigned short hh[4], ll[4];
#pragma unroll
        for (int i = 0; i < 4; i++) {
            float f = tile[c4 + i][r];
            hh[i] = f2bf(f);
            ll[i] = f2bf(f - bf2f(hh[i]));
        }
        size_t off = (size_t)(tn * 32 + r) * D_ + tk * 32 + c4;
        *(uint2*)(Th + off) = make_uint2((unsigned)hh[0] | ((unsigned)hh[1] << 16),
                                         (unsigned)hh[2] | ((unsigned)hh[3] << 16));
        if (wantLo)
            *(uint2*)(Tl + off) = make_uint2((unsigned)ll[0] | ((unsigned)ll[1] << 16),
                                             (unsigned)ll[2] | ((unsigned)ll[3] << 16));
    } else {
        int e = (bid - 3072) * 256 + tid;
        if (e < D_ * DH) {
            int d = e >> 6, j = e & 63;
            float s = 0.f;
#pragma unroll
            for (int hh = 0; hh < H_; hh++) s += Wv[d * D_ + hh * DH + j];
            Wvsh[e] = s * (1.f / 16.f);
        }
        if (e < DH) {
            float s = 0.f;
#pragma unroll
            for (int hh = 0; hh < H_; hh++) s += bv[hh * DH + e];
            bvsh[e] = s * (1.f / 16.f);
        }
    }
}

// ---------------- 64x64 fp32 SGEMM + bias (v_shared, N=64) ----------------
__global__ __launch_bounds__(256) void sgemm64(const float* __restrict__ A,
                                               const float* __restrict__ Bm,
                                               const float* __restrict__ bias,
                                               float* __restrict__ C,
                                               int M, int N, int K) {
    __shared__ float As[16][68];
    __shared__ float Bs[16][68];
    int tid = threadIdx.x;
    int bm = blockIdx.y, bn = blockIdx.x;
    int tx = tid & 15, ty = tid >> 4;
    int la_m = tid >> 2, la_k4 = (tid & 3) * 4;
    int lb_k = tid >> 4, lb_n4 = (tid & 15) * 4;

    float acc[4][4];
#pragma unroll
    for (int i = 0; i < 4; i++)
#pragma unroll
        for (int j = 0; j < 4; j++) acc[i][j] = 0.f;

    for (int k0 = 0; k0 < K; k0 += 16) {
        float4 a4 = *(const float4*)(A + (size_t)(bm * 64 + la_m) * K + k0 + la_k4);
        float4 b4 = *(const float4*)(Bm + (size_t)(k0 + lb_k) * N + bn * 64 + lb_n4);
        __syncthreads();
        As[la_k4 + 0][la_m] = a4.x;
        As[la_k4 + 1][la_m] = a4.y;
        As[la_k4 + 2][la_m] = a4.z;
        As[la_k4 + 3][la_m] = a4.w;
        *(float4*)&Bs[lb_k][lb_n4] = b4;
        __syncthreads();
#pragma unroll
        for (int kk = 0; kk < 16; kk++) {
            float4 a0 = *(float4*)&As[kk][ty * 4];
            float4 b0 = *(float4*)&Bs[kk][tx * 4];
            float av[4] = {a0.x, a0.y, a0.z, a0.w};
            float bw[4] = {b0.x, b0.y, b0.z, b0.w};
#pragma unroll
            for (int i = 0; i < 4; i++)
#pragma unroll
                for (int j = 0; j < 4; j++) acc[i][j] += av[i] * bw[j];
        }
    }
#pragma unroll
    for (int r = 0; r < 4; r++) {
        int row = bm * 64 + ty * 4 + r;
        int col = bn * 64 + tx * 4;
        float4 bb = *(const float4*)(bias + col);
        float4 o;
        o.x = acc[r][0] + bb.x;
        o.y = acc[r][1] + bb.y;
        o.z = acc[r][2] + bb.z;
        o.w = acc[r][3] + bb.w;
        *(float4*)(C + (size_t)row * N + col) = o;
    }
}

// ---------------- bf16 MFMA GEMM, 128x64 tile, B^T layout ----------------
// oscale: output scale applied AFTER bias (exact for powers of 2).
template<int HILO, int OUTMODE>
__global__ __launch_bounds__(256) void bgemm(const float* __restrict__ Afp,
                                             const unsigned short* __restrict__ Abf,
                                             const unsigned short* __restrict__ Bh,
                                             const unsigned short* __restrict__ Bl,
                                             const float* __restrict__ bias,
                                             float oscale,
                                             float* __restrict__ Cf,
                                             unsigned short* __restrict__ Ch,
                                             unsigned short* __restrict__ Cl) {
    __shared__ unsigned short AhS[128 * 32];
    __shared__ unsigned short AlS[HILO ? 128 * 32 : 8];
    __shared__ unsigned short BhS[64 * 32];
    __shared__ unsigned short BlS[HILO ? 64 * 32 : 8];

    int tid = threadIdx.x;
    int bn = blockIdx.x, bm = blockIdx.y;
    int w = tid >> 6, lane = tid & 63;
    int m16 = lane & 15, qd = lane >> 4;
    int rh = (w >> 1) * 64, ch = (w & 1) * 32;

    f32x4 acc[4][2];
#pragma unroll
    for (int it = 0; it < 4; it++)
#pragma unroll
        for (int jt = 0; jt < 2; jt++) acc[it][jt] = (f32x4){0.f, 0.f, 0.f, 0.f};

    for (int k0 = 0; k0 < D_; k0 += 32) {
        __syncthreads();
        if (HILO) {
#pragma unroll
            for (int i = 0; i < 2; i++) {
                int idx = i * 256 + tid;
                int row = idx >> 2, seg = idx & 3;
                const float* src = Afp + (size_t)(bm * 128 + row) * D_ + k0 + seg * 8;
                float4 v0 = *(const float4*)src;
                float4 v1 = *(const float4*)(src + 4);
                float vv[8] = {v0.x, v0.y, v0.z, v0.w, v1.x, v1.y, v1.z, v1.w};
                unsigned int hw[4], lw[4];
#pragma unroll
                for (int j = 0; j < 4; j++) {
                    unsigned short h0 = f2bf(vv[2 * j]), h1 = f2bf(vv[2 * j + 1]);
                    unsigned short l0 = f2bf(vv[2 * j] - bf2f(h0));
                    unsigned short l1 = f2bf(vv[2 * j + 1] - bf2f(h1));
                    hw[j] = (unsigned)h0 | ((unsigned)h1 << 16);
                    lw[j] = (unsigned)l0 | ((unsigned)l1 << 16);
                }
                *(uint4*)((char*)AhS + idx * 16) = make_uint4(hw[0], hw[1], hw[2], hw[3]);
                *(uint4*)((char*)AlS + idx * 16) = make_uint4(lw[0], lw[1], lw[2], lw[3]);
            }
        } else {
#pragma unroll
            for (int i = 0; i < 2; i++) {
                int idx = i * 256 + tid;
                int row = idx >> 2, seg = idx & 3;
                uint4 v = *(const uint4*)(Abf + (size_t)(bm * 128 + row) * D_ + k0 + seg * 8);
                *(uint4*)((char*)AhS + idx * 16) = v;
            }
        }
        {
            int row = tid >> 2, seg = tid & 3;
            uint4 v = *(const uint4*)(Bh + (size_t)(bn * 64 + row) * D_ + k0 + seg * 8);
            *(uint4*)((char*)BhS + tid * 16) = v;
            if (HILO) {
                uint4 v2 = *(const uint4*)(Bl + (size_t)(bn * 64 + row) * D_ + k0 + seg * 8);
                *(uint4*)((char*)BlS + tid * 16) = v2;
            }
        }
        __syncthreads();
        bf16x8 ah[4], al[4], bh2[2], bl2[2];
#pragma unroll
        for (int it = 0; it < 4; it++) {
            ah[it] = *(const bf16x8*)((char*)AhS + (rh + it * 16 + m16) * 64 + qd * 16);
            if (HILO) al[it] = *(const bf16x8*)((char*)AlS + (rh + it * 16 + m16) * 64 + qd * 16);
        }
#pragma unroll
        for (int jt = 0; jt < 2; jt++) {
            bh2[jt] = *(const bf16x8*)((char*)BhS + (ch + jt * 16 + m16) * 64 + qd * 16);
            if (HILO) bl2[jt] = *(const bf16x8*)((char*)BlS + (ch + jt * 16 + m16) * 64 + qd * 16);
        }
#pragma unroll
        for (int it = 0; it < 4; it++)
#pragma unroll
            for (int jt = 0; jt < 2; jt++) {
                acc[it][jt] = __builtin_amdgcn_mfma_f32_16x16x32_bf16(ah[it], bh2[jt], acc[it][jt], 0, 0, 0);
                if (HILO) {
                    acc[it][jt] = __builtin_amdgcn_mfma_f32_16x16x32_bf16(ah[it], bl2[jt], acc[it][jt], 0, 0, 0);
                    acc[it][jt] = __builtin_amdgcn_mfma_f32_16x16x32_bf16(al[it], bh2[jt], acc[it][jt], 0, 0, 0);
                }
            }
    }
#pragma unroll
    for (int it = 0; it < 4; it++)
#pragma unroll
        for (int jt = 0; jt < 2; jt++)
#pragma unroll
            for (int r = 0; r < 4; r++) {
                int R = bm * 128 + rh + it * 16 + qd * 4 + r;
                int Cc = bn * 64 + ch + jt * 16 + m16;
                float v = (acc[it][jt][r] + bias[Cc]) * oscale;
                if (OUTMODE == 0) {
                    Cf[(size_t)R * D_ + Cc] = v;
                } else {
                    unsigned short h0 = f2bf(v);
                    Ch[(size_t)R * D_ + Cc] = h0;
                    Cl[(size_t)R * D_ + Cc] = f2bf(v - bf2f(h0));
                }
            }
}

// ---------------- fused attention v9: 512 threads / 8 waves per block ----------------
// vs v8: each wave covers 128 keys (8 MFMA iters, Cfr[8] = 32 AGPRs) -> per-wave
// serial chain and accumulator footprint both halve; __launch_bounds__(512,4)
// pins <=128 regs so 2 blocks (16 waves) fit per CU. Numerics identical to v8.
#define CCAP 48
__global__ __launch_bounds__(512, 4) void attn9(const unsigned short* __restrict__ qh,
                                                const unsigned short* __restrict__ ql,
                                                const unsigned short* __restrict__ kh,
                                                const unsigned short* __restrict__ kl,
                                                const float* __restrict__ vsh,
                                                unsigned short* __restrict__ och,
                                                unsigned short* __restrict__ sidx,
                                                unsigned short* __restrict__ sval,
                                                int* __restrict__ scnt) {
    __shared__ float smM[8][16];
    __shared__ float smS[8][16], smC[8][16];
    __shared__ float tau0s[16];
    __shared__ float taus[16];
    __shared__ float candV[16][CCAP];
    __shared__ short candI[16][CCAP];
    __shared__ int   ccnt[16];
    __shared__ int   ovfAny;
    __shared__ int   scnt16[16];
    __shared__ short slotI[16][16];
    __shared__ float slotV[16][16];

    int tid = threadIdx.x, w = tid >> 6, lane = tid & 63;
    int m16 = lane & 15, qd = lane >> 4;

    // XCD-aware swizzle: xcd = bid&7 owns bh slices {xcd, 8+xcd, ...}
    int bid = blockIdx.x;
    int xcd = bid & 7;
    int j   = bid >> 3;
    int bh  = ((j & 7) << 3) | xcd;   // 0..63
    int qt  = j >> 3;                 // 0..63
    int bb  = bh >> 4, h = bh & 15;
    int row0g = bb * S_ + qt * 16;
    int kbase = bb * S_;

    // Q A-frags (rows row0g+m16), k-chunks 0/1, hi+lo (pre-scaled by 1/8)
    bf16x8 aH[2], aL[2];
#pragma unroll
    for (int c = 0; c < 2; c++) {
        size_t off = (size_t)(row0g + m16) * D_ + h * DH + c * 32 + qd * 8;
        aH[c] = *(const bf16x8*)(qh + off);
        aL[c] = *(const bf16x8*)(ql + off);
    }

    f32x4 Cfr[8];
#pragma unroll
    for (int t = 0; t < 8; t++) Cfr[t] = (f32x4){0.f, 0.f, 0.f, 0.f};

    // ---- logits: wave w covers keys [w*128, w*128+128); 4 batches of 2 iters ----
#pragma unroll
    for (int tb = 0; tb < 4; tb++) {
        bf16x8 bH[2][2], bL[2][2];
#pragma unroll
        for (int tt = 0; tt < 2; tt++) {
            int n0 = w * 128 + (tb * 2 + tt) * 16;
#pragma unroll
            for (int c = 0; c < 2; c++) {
                size_t boff = (size_t)(kbase + n0 + m16) * D_ + h * DH + c * 32 + qd * 8;
                bH[tt][c] = *(const bf16x8*)(kh + boff);
                bL[tt][c] = *(const bf16x8*)(kl + boff);
            }
        }
#pragma unroll
        for (int tt = 0; tt < 2; tt++) {
            int t = tb * 2 + tt;
            f32x4 a = Cfr[t];
            a = __builtin_amdgcn_mfma_f32_16x16x32_bf16(aH[0], bH[tt][0], a, 0, 0, 0);
            a = __builtin_amdgcn_mfma_f32_16x16x32_bf16(aH[1], bH[tt][1], a, 0, 0, 0);
            a = __builtin_amdgcn_mfma_f32_16x16x32_bf16(aH[0], bL[tt][0], a, 0, 0, 0);
            a = __builtin_amdgcn_mfma_f32_16x16x32_bf16(aH[1], bL[tt][1], a, 0, 0, 0);
            a = __builtin_amdgcn_mfma_f32_16x16x32_bf16(aL[0], bH[tt][0], a, 0, 0, 0);
            a = __builtin_amdgcn_mfma_f32_16x16x32_bf16(aL[1], bH[tt][1], a, 0, 0, 0);
            Cfr[t] = a;
        }
    }

    // ---- row max -> tau0 ----
    float mxr[4];
#pragma unroll
    for (int r = 0; r < 4; r++) mxr[r] = -3.0e38f;
#pragma unroll
    for (int t = 0; t < 8; t++)
#pragma unroll
        for (int r = 0; r < 4; r++) mxr[r] = fmaxf(mxr[r], Cfr[t][r]);
#pragma unroll
    for (int off = 8; off >= 1; off >>= 1)
#pragma unroll
        for (int r = 0; r < 4; r++) mxr[r] = fmaxf(mxr[r], __shfl_xor(mxr[r], off, 16));
    if (m16 == 0)
#pragma unroll
        for (int r = 0; r < 4; r++) smM[w][qd * 4 + r] = mxr[r];
    if (tid < 16) ccnt[tid] = 0;
    if (tid == 0) ovfAny = 0;
    __syncthreads();
    if (tid < 16) {
        float m = smM[0][tid];
#pragma unroll
        for (int ww = 1; ww < 8; ww++) m = fmaxf(m, smM[ww][tid]);
        tau0s[tid] = m - 1.0f;
    }
    __syncthreads();

    // ---- candidate compaction (val + idx) ----
#pragma unroll
    for (int t = 0; t < 8; t++)
#pragma unroll
        for (int r = 0; r < 4; r++) {
            float z = Cfr[t][r];
            int row = qd * 4 + r;
            if (z > tau0s[row]) {
                int pos = atomicAdd(&ccnt[row], 1);
                if (pos < CCAP) {
                    candV[row][pos] = z;
                    candI[row][pos] = (short)(w * 128 + t * 16 + m16);
                }
            }
        }
    __syncthreads();
    if (tid < 16 && ccnt[tid] > CCAP) ovfAny = 1;

    // ---- fast-path Newton over candidates: 16 threads per row (tid<256) ----
    int prow = (tid >> 4) & 15, pc = tid & 15;
    float tau = 0.f;
    float z0 = -3.0e38f, z1 = -3.0e38f, z2 = -3.0e38f;
    if (tid < 256) {
        int nc = ccnt[prow];
        tau = tau0s[prow];
        if (nc <= CCAP) {
            z0 = (pc < nc)      ? candV[prow][pc]      : -3.0e38f;
            z1 = (pc + 16 < nc) ? candV[prow][pc + 16] : -3.0e38f;
            z2 = (pc + 32 < nc) ? candV[prow][pc + 32] : -3.0e38f;
            for (int it = 0; it < CCAP; it++) {
                float s = 0.f, c = 0.f;
                if (z0 > tau) { s += z0; c += 1.f; }
                if (z1 > tau) { s += z1; c += 1.f; }
                if (z2 > tau) { s += z2; c += 1.f; }
#pragma unroll
                for (int off = 8; off >= 1; off >>= 1) {
                    s += __shfl_xor(s, off, 16);
                    c += __shfl_xor(c, off, 16);
                }
                float tnew = (s - 1.f) / c;
                if (tnew > tau) tau = tnew; else break;
            }
        }
        if (pc == 0) taus[prow] = tau;   // overflow rows keep tau0
    }
    if (tid < 16) scnt16[tid] = 0;
    __syncthreads();

    if (!ovfAny) {
        // ---- fast-path slot extraction from candidate list (3 entries/lane) ----
        if (tid < 256) {
            if (z0 > tau) {
                int sl = atomicAdd(&scnt16[prow], 1);
                if (sl < 16) { slotI[prow][sl] = candI[prow][pc]; slotV[prow][sl] = z0 - tau; }
            }
            if (z1 > tau) {
                int sl = atomicAdd(&scnt16[prow], 1);
                if (sl < 16) { slotI[prow][sl] = candI[prow][pc + 16]; slotV[prow][sl] = z1 - tau; }
            }
            if (z2 > tau) {
                int sl = atomicAdd(&scnt16[prow], 1);
                if (sl < 16) { slotI[prow][sl] = candI[prow][pc + 32]; slotV[prow][sl] = z2 - tau; }
            }
        }
        __syncthreads();
    } else {
        // ---- rare fallback: full-register block Newton + register extraction ----
        for (int it = 0; it < 64; it++) {
            float s[4], c[4];
#pragma unroll
            for (int r = 0; r < 4; r++) { s[r] = 0.f; c[r] = 0.f; }
#pragma unroll
            for (int t = 0; t < 8; t++)
#pragma unroll
                for (int r = 0; r < 4; r++) {
                    float z = Cfr[t][r];
                    if (z > taus[qd * 4 + r]) { s[r] += z; c[r] += 1.f; }
                }
#pragma unroll
            for (int off = 8; off >= 1; off >>= 1)
#pragma unroll
                for (int r = 0; r < 4; r++) {
                    s[r] += __shfl_xor(s[r], off, 16);
                    c[r] += __shfl_xor(c[r], off, 16);
                }
            if (m16 == 0)
#pragma unroll
                for (int r = 0; r < 4; r++) {
                    smS[w][qd * 4 + r] = s[r];
                    smC[w][qd * 4 + r] = c[r];
                }
            __syncthreads();
            int done = 1;
            if (tid < 16) {
                float S = 0.f, C = 0.f;
#pragma unroll
                for (int ww = 0; ww < 8; ww++) { S += smS[ww][tid]; C += smC[ww][tid]; }
                float tnew = (S - 1.f) / C;
                if (C > 0.f && tnew > taus[tid]) { taus[tid] = tnew; done = 0; }
            }
            if (__syncthreads_and(done)) break;
        }
#pragma unroll
        for (int t = 0; t < 8; t++)
#pragma unroll
            for (int r = 0; r < 4; r++) {
                int row = qd * 4 + r;
                float p = Cfr[t][r] - taus[row];
                if (p > 0.f) {
                    int sl = atomicAdd(&scnt16[row], 1);
                    if (sl < 16) {
                        slotI[row][sl] = (short)(w * 128 + t * 16 + m16);
                        slotV[row][sl] = p;
                    }
                }
            }
        __syncthreads();
    }

    // ---- PV + och write + export: threads < 256 (16 lanes per row) ----
    if (tid < 256) {
        int nsl = min(scnt16[prow], 16);
        float4 accq = make_float4(0.f, 0.f, 0.f, 0.f);
        for (int sl = 0; sl < nsl; sl++) {
            int key = slotI[prow][sl];
            float p = slotV[prow][sl];
            float4 vv = *(const float4*)(vsh + (size_t)(kbase + key) * DH + pc * 4);
            accq.x += p * vv.x;
            accq.y += p * vv.y;
            accq.z += p * vv.z;
            accq.w += p * vv.w;
        }
        {
            unsigned short b0 = f2bf(accq.x), b1 = f2bf(accq.y), b2 = f2bf(accq.z), b3 = f2bf(accq.w);
            *(uint2*)(och + (size_t)(row0g + prow) * D_ + h * DH + pc * 4) =
                make_uint2((unsigned)b0 | ((unsigned)b1 << 16), (unsigned)b2 | ((unsigned)b3 << 16));
        }
        {
            size_t base = ((size_t)(row0g + prow) * H_ + h) * 16;
            if (pc == 0) scnt[(row0g + prow) * H_ + h] = nsl;
            if (pc < nsl) {
                sidx[base + pc] = (unsigned short)slotI[prow][pc];
                sval[base + pc] = f2bf(slotV[prow][pc]);
            }
        }
    }
}

// ---------------- avg_attention: per-row reduction over 16 heads ----------------
__global__ __launch_bounds__(256) void avg_reduce(const unsigned short* __restrict__ sidx,
                                                  const unsigned short* __restrict__ sval,
                                                  const int* __restrict__ scnt,
                                                  float* __restrict__ avg) {
    __shared__ float accv[1024];
    int tid = threadIdx.x;
    int grow = blockIdx.x;
    for (int i = tid; i < 1024; i += 256) accv[i] = 0.f;
    __syncthreads();
    int h = tid >> 4, sl = tid & 15;
    int n = scnt[grow * H_ + h];
    if (sl < n) {
        size_t base = ((size_t)grow * H_ + h) * 16;
        int idx = sidx[base + sl];
        float v = bf2f(sval[base + sl]);
        atomicAdd(&accv[idx], v);
    }
    __syncthreads();
    float* dst = avg + (size_t)grow * S_;
    for (int i = tid; i < 256; i += 256) {
        float4 o;
        o.x = accv[i * 4 + 0] * 0.0625f;
        o.y = accv[i * 4 + 1] * 0.0625f;
        o.z = accv[i * 4 + 2] * 0.0625f;
        o.w = accv[i * 4 + 3] * 0.0625f;
        *(float4*)(dst + i * 4) = o;
    }
}

extern "C" void kernel_launch(void* const* d_in, const int* in_sizes, int n_in,
                              void* d_out, int out_size, void* d_ws, size_t ws_size,
                              hipStream_t stream) {
    const float* x  = (const float*)d_in[0];
    const float* Wq = (const float*)d_in[1];
    const float* bq = (const float*)d_in[2];
    const float* Wk = (const float*)d_in[3];
    const float* bk = (const float*)d_in[4];
    const float* Wv = (const float*)d_in[5];
    const float* bv = (const float*)d_in[6];
    const float* Wo = (const float*)d_in[7];
    const float* bo = (const float*)d_in[8];

    float* xout = (float*)d_out;                   // (B,S,D)
    float* avg  = xout + (size_t)BS * D_;          // (B,S,S)

    char* ws = (char*)d_ws;
    unsigned short* qhB  = (unsigned short*)(ws + 0);               // 8 MB
    unsigned short* qlB  = (unsigned short*)(ws + (8u << 20));      // 8 MB
    unsigned short* khB  = (unsigned short*)(ws + (16u << 20));     // 8 MB
    unsigned short* klB  = (unsigned short*)(ws + (24u << 20));     // 8 MB
    unsigned short* WqTh = (unsigned short*)(ws + (32u << 20));     // 2 MB
    unsigned short* WqTl = (unsigned short*)(ws + (34u << 20));     // 2 MB
    unsigned short* WkTh = (unsigned short*)(ws + (36u << 20));     // 2 MB
    unsigned short* WkTl = (unsigned short*)(ws + (38u << 20));     // 2 MB
    unsigned short* ochB = WqTh;                                    // 8 MB alias (32..40), dead after bgemms
    unsigned short* WoTh = (unsigned short*)(ws + (40u << 20));     // 2 MB
    float* vshb = (float*)(ws + (42u << 20));                       // 1 MB
    float* Wvsh = (float*)(ws + (43u << 20));                       // 256 KB
    float* bvsh = (float*)(ws + (43u << 20) + (300u << 10));        // tiny
    unsigned short* sidx = (unsigned short*)(ws + (44u << 20));     // 2 MB
    unsigned short* sval = (unsigned short*)(ws + (46u << 20));     // 2 MB
    int* scnt = (int*)(ws + (48u << 20));                           // 256 KB

    dim3 ggrid(D_ / 64, BS / 128);

    prep<<<3328, 256, 0, stream>>>(Wq, Wk, Wo, Wv, bv, WqTh, WqTl, WkTh, WkTl, WoTh, Wvsh, bvsh);
    bgemm<1, 1><<<ggrid, 256, 0, stream>>>(x, nullptr, WqTh, WqTl, bq, 0.125f, nullptr, qhB, qlB);
    bgemm<1, 1><<<ggrid, 256, 0, stream>>>(x, nullptr, WkTh, WkTl, bk, 1.0f, nullptr, khB, klB);
    sgemm64<<<dim3(1, BS / 64), 256, 0, stream>>>(x, Wvsh, bvsh, vshb, BS, DH, D_);
    attn9<<<4096, 512, 0, stream>>>(qhB, qlB, khB, klB, vshb, ochB, sidx, sval, scnt);
    avg_reduce<<<4096, 256, 0, stream>>>(sidx, sval, scnt, avg);
    bgemm<0, 0><<<ggrid, 256, 0, stream>>>(nullptr, ochB, WoTh, nullptr, bo, 1.0f, xout, nullptr, nullptr);
}

// Round 9
// 396.963 us; speedup vs baseline: 1.1885x; 1.1885x over previous
//
#include <hip/hip_runtime.h>

#define B_  4
#define S_  1024
#define D_  1024
#define H_  16
#define DH  64
#define BS  4096   // B_*S_

typedef __bf16 bf16x8 __attribute__((ext_vector_type(8)));
typedef float  f32x4  __attribute__((ext_vector_type(4)));

__device__ __forceinline__ unsigned short f2bf(float f) {
    __bf16 b = (__bf16)f;
    return __builtin_bit_cast(unsigned short, b);
}
__device__ __forceinline__ float bf2f(unsigned short u) {
    return (float)__builtin_bit_cast(__bf16, u);
}
// async global->LDS, 16B/lane; LDS dest = wave-uniform base + lane*16
__device__ __forceinline__ void glds16(const void* g, void* l) {
    __builtin_amdgcn_global_load_lds((const __attribute__((address_space(1))) void*)g,
                                     (__attribute__((address_space(3))) void*)l, 16, 0, 0);
}

// ---------------- prep2: weight transp+hi/lo splits, Wvsh^T (padded) split, bvp ----------------
__global__ __launch_bounds__(256) void prep2(const float* __restrict__ Wq,
                                             const float* __restrict__ Wk,
                                             const float* __restrict__ Wo,
                                             const float* __restrict__ Wv,
                                             const float* __restrict__ bv,
                                             unsigned short* __restrict__ WqTh,
                                             unsigned short* __restrict__ WqTl,
                                             unsigned short* __restrict__ WkTh,
                                             unsigned short* __restrict__ WkTl,
                                             unsigned short* __restrict__ WoTh,
                                             unsigned short* __restrict__ WvTh,
                                             unsigned short* __restrict__ WvTl,
                                             float* __restrict__ bvp) {
    __shared__ float tile[32][33];
    int bid = blockIdx.x, tid = threadIdx.x;
    if (bid < 3072) {
        const float* W;
        unsigned short *Th, *Tl;
        int wantLo;
        if (bid < 1024)      { W = Wq; Th = WqTh; Tl = WqTl; wantLo = 1; }
        else if (bid < 2048) { W = Wk; Th = WkTh; Tl = WkTl; wantLo = 1; bid -= 1024; }
        else                 { W = Wo; Th = WoTh; Tl = nullptr; wantLo = 0; bid -= 2048; }
        int tn = bid & 31, tk = bid >> 5;
        int r = tid >> 3, c4 = (tid & 7) * 4;
        float4 v = *(const float4*)(W + (size_t)(tk * 32 + r) * D_ + tn * 32 + c4);
        tile[r][c4 + 0] = v.x;
        tile[r][c4 + 1] = v.y;
        tile[r][c4 + 2] = v.z;
        tile[r][c4 + 3] = v.w;
        __syncthreads();
        unsigned short hh[4], ll[4];
#pragma unroll
        for (int i = 0; i < 4; i++) {
            float f = tile[c4 + i][r];
            hh[i] = f2bf(f);
            ll[i] = f2bf(f - bf2f(hh[i]));
        }
        size_t off = (size_t)(tn * 32 + r) * D_ + tk * 32 + c4;
        *(uint2*)(Th + off) = make_uint2((unsigned)hh[0] | ((unsigned)hh[1] << 16),
                                         (unsigned)hh[2] | ((unsigned)hh[3] << 16));
        if (wantLo)
            *(uint2*)(Tl + off) = make_uint2((unsigned)ll[0] | ((unsigned)ll[1] << 16),
                                             (unsigned)ll[2] | ((unsigned)ll[3] << 16));
    } else if (bid < 3328) {
        // Wvsh^T rows 0..63: WvT[j][d] = mean_h Wv[d][h*64+j], hi/lo
        int e = (bid - 3072) * 256 + tid;      // 0..65535
        int d = e >> 6, j = e & 63;
        float s = 0.f;
#pragma unroll
        for (int hh = 0; hh < H_; hh++) s += Wv[(size_t)d * D_ + hh * DH + j];
        s *= (1.f / 16.f);
        unsigned short hi = f2bf(s);
        WvTh[(size_t)j * D_ + d] = hi;
        WvTl[(size_t)j * D_ + d] = f2bf(s - bf2f(hi));
        if (bid == 3072 && tid < 128) {
            float sb = 0.f;
            if (tid < 64) {
#pragma unroll
                for (int hh = 0; hh < H_; hh++) sb += bv[hh * DH + tid];
                sb *= (1.f / 16.f);
            }
            bvp[tid] = sb;
        }
    } else {
        // zero-pad rows 64..127 of Wvsh^T
        int e = (bid - 3328) * 256 + tid;      // 0..65535
        int row = 64 + (e >> 10), col = e & 1023;
        WvTh[(size_t)row * D_ + col] = 0;
        WvTl[(size_t)row * D_ + col] = 0;
    }
}

// ---------------- projg: fused Q/K/v_shared projection, 128x128 tile, hilo, B via glds ----------------
// grid (17, 32): bn<8 -> Q cols, bn<16 -> K cols, bn==16 -> v_shared (padded tile)
__global__ __launch_bounds__(256) void projg(const float* __restrict__ x,
                                             const unsigned short* __restrict__ WqTh, const unsigned short* __restrict__ WqTl,
                                             const unsigned short* __restrict__ WkTh, const unsigned short* __restrict__ WkTl,
                                             const unsigned short* __restrict__ WvTh, const unsigned short* __restrict__ WvTl,
                                             const float* __restrict__ bq, const float* __restrict__ bk,
                                             const float* __restrict__ bvp,
                                             unsigned short* __restrict__ qh, unsigned short* __restrict__ ql,
                                             unsigned short* __restrict__ kh, unsigned short* __restrict__ kl,
                                             float* __restrict__ vshb) {
    __shared__ unsigned short AhS[128 * 32];
    __shared__ unsigned short AlS[128 * 32];
    __shared__ unsigned short BhS[128 * 32];
    __shared__ unsigned short BlS[128 * 32];

    int tid = threadIdx.x, w = tid >> 6, lane = tid & 63;
    int m16 = lane & 15, qd = lane >> 4;
    int bn = blockIdx.x, bm = blockIdx.y;

    const unsigned short *Bh, *Bl;
    const float* bias;
    int mode;
    if (bn < 8)       { Bh = WqTh + (size_t)bn * 128 * D_;       Bl = WqTl + (size_t)bn * 128 * D_;       bias = bq + bn * 128;       mode = 0; }
    else if (bn < 16) { Bh = WkTh + (size_t)(bn - 8) * 128 * D_; Bl = WkTl + (size_t)(bn - 8) * 128 * D_; bias = bk + (bn - 8) * 128; mode = 1; }
    else              { Bh = WvTh; Bl = WvTl; bias = bvp; mode = 2; }

    int l4 = lane >> 2, c8 = (lane & 3) * 8;     // staging: row offset, k offset (elems)
    int rh = (w >> 1) * 64, chh = (w & 1) * 64;  // wave quadrant

    f32x4 acc[4][4];
#pragma unroll
    for (int it = 0; it < 4; it++)
#pragma unroll
        for (int jt = 0; jt < 4; jt++) acc[it][jt] = (f32x4){0.f, 0.f, 0.f, 0.f};

    int ra = tid >> 1, ca = (tid & 1) * 16;      // A staging: 16 floats/thread

    for (int k0 = 0; k0 < D_; k0 += 32) {
        // A: fp32 -> bf16 hi/lo (issue loads before barrier for overlap)
        const float* ax = x + (size_t)(bm * 128 + ra) * D_ + k0 + ca;
        float4 f0 = *(const float4*)(ax + 0);
        float4 f1 = *(const float4*)(ax + 4);
        float4 f2 = *(const float4*)(ax + 8);
        float4 f3 = *(const float4*)(ax + 12);
        __syncthreads();
        {
            float vv[16] = {f0.x, f0.y, f0.z, f0.w, f1.x, f1.y, f1.z, f1.w,
                            f2.x, f2.y, f2.z, f2.w, f3.x, f3.y, f3.z, f3.w};
            unsigned int hw[8], lw[8];
#pragma unroll
            for (int i = 0; i < 8; i++) {
                unsigned short h0 = f2bf(vv[2 * i]), h1 = f2bf(vv[2 * i + 1]);
                unsigned short l0 = f2bf(vv[2 * i] - bf2f(h0));
                unsigned short l1 = f2bf(vv[2 * i + 1] - bf2f(h1));
                hw[i] = (unsigned)h0 | ((unsigned)h1 << 16);
                lw[i] = (unsigned)l0 | ((unsigned)l1 << 16);
            }
            char* ah = (char*)AhS + ra * 64 + ca * 2;
            char* al = (char*)AlS + ra * 64 + ca * 2;
            *(uint4*)(ah + 0)  = make_uint4(hw[0], hw[1], hw[2], hw[3]);
            *(uint4*)(ah + 16) = make_uint4(hw[4], hw[5], hw[6], hw[7]);
            *(uint4*)(al + 0)  = make_uint4(lw[0], lw[1], lw[2], lw[3]);
            *(uint4*)(al + 16) = make_uint4(lw[4], lw[5], lw[6], lw[7]);
        }
        // B: async glds, wave w stages tile rows w*32..w*32+32
        {
            const unsigned short* gbh = Bh + (size_t)(w * 32 + l4) * D_ + k0 + c8;
            const unsigned short* gbl = Bl + (size_t)(w * 32 + l4) * D_ + k0 + c8;
            glds16(gbh,                     (char*)BhS + w * 2048);
            glds16(gbh + (size_t)16 * D_,   (char*)BhS + w * 2048 + 1024);
            glds16(gbl,                     (char*)BlS + w * 2048);
            glds16(gbl + (size_t)16 * D_,   (char*)BlS + w * 2048 + 1024);
        }
        __syncthreads();
        bf16x8 ah[4], al[4], bh[4], bl[4];
#pragma unroll
        for (int it = 0; it < 4; it++) {
            ah[it] = *(const bf16x8*)((char*)AhS + (rh + it * 16 + m16) * 64 + qd * 16);
            al[it] = *(const bf16x8*)((char*)AlS + (rh + it * 16 + m16) * 64 + qd * 16);
        }
#pragma unroll
        for (int jt = 0; jt < 4; jt++) {
            bh[jt] = *(const bf16x8*)((char*)BhS + (chh + jt * 16 + m16) * 64 + qd * 16);
            bl[jt] = *(const bf16x8*)((char*)BlS + (chh + jt * 16 + m16) * 64 + qd * 16);
        }
#pragma unroll
        for (int it = 0; it < 4; it++)
#pragma unroll
            for (int jt = 0; jt < 4; jt++) {
                acc[it][jt] = __builtin_amdgcn_mfma_f32_16x16x32_bf16(ah[it], bh[jt], acc[it][jt], 0, 0, 0);
                acc[it][jt] = __builtin_amdgcn_mfma_f32_16x16x32_bf16(ah[it], bl[jt], acc[it][jt], 0, 0, 0);
                acc[it][jt] = __builtin_amdgcn_mfma_f32_16x16x32_bf16(al[it], bh[jt], acc[it][jt], 0, 0, 0);
            }
    }
#pragma unroll
    for (int it = 0; it < 4; it++)
#pragma unroll
        for (int jt = 0; jt < 4; jt++)
#pragma unroll
            for (int r = 0; r < 4; r++) {
                int R = bm * 128 + rh + it * 16 + qd * 4 + r;
                int c = chh + jt * 16 + m16;
                float v = acc[it][jt][r] + bias[c];
                if (mode == 0) {
                    v *= 0.125f;
                    unsigned short h0 = f2bf(v);
                    qh[(size_t)R * D_ + bn * 128 + c] = h0;
                    ql[(size_t)R * D_ + bn * 128 + c] = f2bf(v - bf2f(h0));
                } else if (mode == 1) {
                    unsigned short h0 = f2bf(v);
                    kh[(size_t)R * D_ + (bn - 8) * 128 + c] = h0;
                    kl[(size_t)R * D_ + (bn - 8) * 128 + c] = f2bf(v - bf2f(h0));
                } else {
                    if (c < 64) vshb[(size_t)R * 64 + c] = v;
                }
            }
}

// ---------------- outg: x_out = och @ Wo + bo, 128x128 tile, bf16 single, all glds ----------------
__global__ __launch_bounds__(256) void outg(const unsigned short* __restrict__ A,
                                            const unsigned short* __restrict__ Bh,
                                            const float* __restrict__ bias,
                                            float* __restrict__ C) {
    __shared__ unsigned short AhS[128 * 32];
    __shared__ unsigned short BhS[128 * 32];

    int tid = threadIdx.x, w = tid >> 6, lane = tid & 63;
    int m16 = lane & 15, qd = lane >> 4;
    int bn = blockIdx.x, bm = blockIdx.y;
    int l4 = lane >> 2, c8 = (lane & 3) * 8;
    int rh = (w >> 1) * 64, chh = (w & 1) * 64;

    f32x4 acc[4][4];
#pragma unroll
    for (int it = 0; it < 4; it++)
#pragma unroll
        for (int jt = 0; jt < 4; jt++) acc[it][jt] = (f32x4){0.f, 0.f, 0.f, 0.f};

    for (int k0 = 0; k0 < D_; k0 += 32) {
        __syncthreads();
        {
            const unsigned short* ga = A + (size_t)(bm * 128 + w * 32 + l4) * D_ + k0 + c8;
            glds16(ga,                   (char*)AhS + w * 2048);
            glds16(ga + (size_t)16 * D_, (char*)AhS + w * 2048 + 1024);
            const unsigned short* gb = Bh + (size_t)(bn * 128 + w * 32 + l4) * D_ + k0 + c8;
            glds16(gb,                   (char*)BhS + w * 2048);
            glds16(gb + (size_t)16 * D_, (char*)BhS + w * 2048 + 1024);
        }
        __syncthreads();
        bf16x8 ah[4], bh[4];
#pragma unroll
        for (int it = 0; it < 4; it++)
            ah[it] = *(const bf16x8*)((char*)AhS + (rh + it * 16 + m16) * 64 + qd * 16);
#pragma unroll
        for (int jt = 0; jt < 4; jt++)
            bh[jt] = *(const bf16x8*)((char*)BhS + (chh + jt * 16 + m16) * 64 + qd * 16);
#pragma unroll
        for (int it = 0; it < 4; it++)
#pragma unroll
            for (int jt = 0; jt < 4; jt++)
                acc[it][jt] = __builtin_amdgcn_mfma_f32_16x16x32_bf16(ah[it], bh[jt], acc[it][jt], 0, 0, 0);
    }
#pragma unroll
    for (int it = 0; it < 4; it++)
#pragma unroll
        for (int jt = 0; jt < 4; jt++)
#pragma unroll
            for (int r = 0; r < 4; r++) {
                int R = bm * 128 + rh + it * 16 + qd * 4 + r;
                int cc = bn * 128 + chh + jt * 16 + m16;
                C[(size_t)R * D_ + cc] = acc[it][jt][r] + bias[cc];
            }
}

// ---------------- fused attention v8 (round-7 proven, verbatim) ----------------
#define CCAP 48
__global__ __launch_bounds__(256, 2) void attn8(const unsigned short* __restrict__ qh,
                                                const unsigned short* __restrict__ ql,
                                                const unsigned short* __restrict__ kh,
                                                const unsigned short* __restrict__ kl,
                                                const float* __restrict__ vsh,
                                                unsigned short* __restrict__ och,
                                                unsigned short* __restrict__ sidx,
                                                unsigned short* __restrict__ sval,
                                                int* __restrict__ scnt) {
    __shared__ float smM[4][16];
    __shared__ float smS[4][16], smC[4][16];
    __shared__ float tau0s[16];
    __shared__ float taus[16];
    __shared__ float candV[16][CCAP];
    __shared__ short candI[16][CCAP];
    __shared__ int   ccnt[16];
    __shared__ int   ovfAny;
    __shared__ int   scnt16[16];
    __shared__ short slotI[16][16];
    __shared__ float slotV[16][16];

    int tid = threadIdx.x, w = tid >> 6, lane = tid & 63;
    int m16 = lane & 15, qd = lane >> 4;

    int bid = blockIdx.x;
    int xcd = bid & 7;
    int j   = bid >> 3;
    int bh  = ((j & 7) << 3) | xcd;
    int qt  = j >> 3;
    int bb  = bh >> 4, h = bh & 15;
    int row0g = bb * S_ + qt * 16;
    int kbase = bb * S_;

    bf16x8 aH[2], aL[2];
#pragma unroll
    for (int c = 0; c < 2; c++) {
        size_t off = (size_t)(row0g + m16) * D_ + h * DH + c * 32 + qd * 8;
        aH[c] = *(const bf16x8*)(qh + off);
        aL[c] = *(const bf16x8*)(ql + off);
    }

    f32x4 Cfr[16];
#pragma unroll
    for (int t = 0; t < 16; t++) Cfr[t] = (f32x4){0.f, 0.f, 0.f, 0.f};

#pragma unroll
    for (int tb = 0; tb < 4; tb++) {
        bf16x8 bH[4][2], bL[4][2];
#pragma unroll
        for (int tt = 0; tt < 4; tt++) {
            int n0 = w * 256 + (tb * 4 + tt) * 16;
#pragma unroll
            for (int c = 0; c < 2; c++) {
                size_t boff = (size_t)(kbase + n0 + m16) * D_ + h * DH + c * 32 + qd * 8;
                bH[tt][c] = *(const bf16x8*)(kh + boff);
                bL[tt][c] = *(const bf16x8*)(kl + boff);
            }
        }
#pragma unroll
        for (int tt = 0; tt < 4; tt++) {
            int t = tb * 4 + tt;
            f32x4 a = Cfr[t];
            a = __builtin_amdgcn_mfma_f32_16x16x32_bf16(aH[0], bH[tt][0], a, 0, 0, 0);
            a = __builtin_amdgcn_mfma_f32_16x16x32_bf16(aH[1], bH[tt][1], a, 0, 0, 0);
            a = __builtin_amdgcn_mfma_f32_16x16x32_bf16(aH[0], bL[tt][0], a, 0, 0, 0);
            a = __builtin_amdgcn_mfma_f32_16x16x32_bf16(aH[1], bL[tt][1], a, 0, 0, 0);
            a = __builtin_amdgcn_mfma_f32_16x16x32_bf16(aL[0], bH[tt][0], a, 0, 0, 0);
            a = __builtin_amdgcn_mfma_f32_16x16x32_bf16(aL[1], bH[tt][1], a, 0, 0, 0);
            Cfr[t] = a;
        }
    }

    float mxr[4];
#pragma unroll
    for (int r = 0; r < 4; r++) mxr[r] = -3.0e38f;
#pragma unroll
    for (int t = 0; t < 16; t++)
#pragma unroll
        for (int r = 0; r < 4; r++) mxr[r] = fmaxf(mxr[r], Cfr[t][r]);
#pragma unroll
    for (int off = 8; off >= 1; off >>= 1)
#pragma unroll
        for (int r = 0; r < 4; r++) mxr[r] = fmaxf(mxr[r], __shfl_xor(mxr[r], off, 16));
    if (m16 == 0)
#pragma unroll
        for (int r = 0; r < 4; r++) smM[w][qd * 4 + r] = mxr[r];
    if (tid < 16) ccnt[tid] = 0;
    if (tid == 0) ovfAny = 0;
    __syncthreads();
    if (tid < 16)
        tau0s[tid] = fmaxf(fmaxf(smM[0][tid], smM[1][tid]), fmaxf(smM[2][tid], smM[3][tid])) - 1.0f;
    __syncthreads();

#pragma unroll
    for (int t = 0; t < 16; t++)
#pragma unroll
        for (int r = 0; r < 4; r++) {
            float z = Cfr[t][r];
            int row = qd * 4 + r;
            if (z > tau0s[row]) {
                int pos = atomicAdd(&ccnt[row], 1);
                if (pos < CCAP) {
                    candV[row][pos] = z;
                    candI[row][pos] = (short)(w * 256 + t * 16 + m16);
                }
            }
        }
    __syncthreads();
    if (tid < 16 && ccnt[tid] > CCAP) ovfAny = 1;

    int prow = tid >> 4, pc = tid & 15;
    int nc = ccnt[prow];
    float tau = tau0s[prow];
    float z0 = -3.0e38f, z1 = -3.0e38f, z2 = -3.0e38f;
    if (nc <= CCAP) {
        z0 = (pc < nc)      ? candV[prow][pc]      : -3.0e38f;
        z1 = (pc + 16 < nc) ? candV[prow][pc + 16] : -3.0e38f;
        z2 = (pc + 32 < nc) ? candV[prow][pc + 32] : -3.0e38f;
        for (int it = 0; it < CCAP; it++) {
            float s = 0.f, c = 0.f;
            if (z0 > tau) { s += z0; c += 1.f; }
            if (z1 > tau) { s += z1; c += 1.f; }
            if (z2 > tau) { s += z2; c += 1.f; }
#pragma unroll
            for (int off = 8; off >= 1; off >>= 1) {
                s += __shfl_xor(s, off, 16);
                c += __shfl_xor(c, off, 16);
            }
            float tnew = (s - 1.f) / c;
            if (tnew > tau) tau = tnew; else break;
        }
    }
    if (pc == 0) taus[prow] = tau;
    if (tid < 16) scnt16[tid] = 0;
    __syncthreads();

    if (!ovfAny) {
        if (z0 > tau) {
            int sl = atomicAdd(&scnt16[prow], 1);
            if (sl < 16) { slotI[prow][sl] = candI[prow][pc]; slotV[prow][sl] = z0 - tau; }
        }
        if (z1 > tau) {
            int sl = atomicAdd(&scnt16[prow], 1);
            if (sl < 16) { slotI[prow][sl] = candI[prow][pc + 16]; slotV[prow][sl] = z1 - tau; }
        }
        if (z2 > tau) {
            int sl = atomicAdd(&scnt16[prow], 1);
            if (sl < 16) { slotI[prow][sl] = candI[prow][pc + 32]; slotV[prow][sl] = z2 - tau; }
        }
        __syncthreads();
    } else {
        for (int it = 0; it < 64; it++) {
            float s[4], c[4];
#pragma unroll
            for (int r = 0; r < 4; r++) { s[r] = 0.f; c[r] = 0.f; }
#pragma unroll
            for (int t = 0; t < 16; t++)
#pragma unroll
                for (int r = 0; r < 4; r++) {
                    float z = Cfr[t][r];
                    if (z > taus[qd * 4 + r]) { s[r] += z; c[r] += 1.f; }
                }
#pragma unroll
            for (int off = 8; off >= 1; off >>= 1)
#pragma unroll
                for (int r = 0; r < 4; r++) {
                    s[r] += __shfl_xor(s[r], off, 16);
                    c[r] += __shfl_xor(c[r], off, 16);
                }
            if (m16 == 0)
#pragma unroll
                for (int r = 0; r < 4; r++) {
                    smS[w][qd * 4 + r] = s[r];
                    smC[w][qd * 4 + r] = c[r];
                }
            __syncthreads();
            int done = 1;
            if (tid < 16) {
                float S = smS[0][tid] + smS[1][tid] + smS[2][tid] + smS[3][tid];
                float C = smC[0][tid] + smC[1][tid] + smC[2][tid] + smC[3][tid];
                float tnew = (S - 1.f) / C;
                if (C > 0.f && tnew > taus[tid]) { taus[tid] = tnew; done = 0; }
            }
            if (__syncthreads_and(done)) break;
        }
#pragma unroll
        for (int t = 0; t < 16; t++)
#pragma unroll
            for (int r = 0; r < 4; r++) {
                int row = qd * 4 + r;
                float p = Cfr[t][r] - taus[row];
                if (p > 0.f) {
                    int sl = atomicAdd(&scnt16[row], 1);
                    if (sl < 16) {
                        slotI[row][sl] = (short)(w * 256 + t * 16 + m16);
                        slotV[row][sl] = p;
                    }
                }
            }
        __syncthreads();
    }

    int nsl = min(scnt16[prow], 16);
    float4 accq = make_float4(0.f, 0.f, 0.f, 0.f);
    for (int sl = 0; sl < nsl; sl++) {
        int key = slotI[prow][sl];
        float p = slotV[prow][sl];
        float4 vv = *(const float4*)(vsh + (size_t)(kbase + key) * DH + pc * 4);
        accq.x += p * vv.x;
        accq.y += p * vv.y;
        accq.z += p * vv.z;
        accq.w += p * vv.w;
    }
    {
        unsigned short b0 = f2bf(accq.x), b1 = f2bf(accq.y), b2 = f2bf(accq.z), b3 = f2bf(accq.w);
        *(uint2*)(och + (size_t)(row0g + prow) * D_ + h * DH + pc * 4) =
            make_uint2((unsigned)b0 | ((unsigned)b1 << 16), (unsigned)b2 | ((unsigned)b3 << 16));
    }
    {
        size_t base = ((size_t)(row0g + prow) * H_ + h) * 16;
        if (pc == 0) scnt[(row0g + prow) * H_ + h] = nsl;
        if (pc < nsl) {
            sidx[base + pc] = (unsigned short)slotI[prow][pc];
            sval[base + pc] = f2bf(slotV[prow][pc]);
        }
    }
}

// ---------------- avg_attention: per-row reduction over 16 heads ----------------
__global__ __launch_bounds__(256) void avg_reduce(const unsigned short* __restrict__ sidx,
                                                  const unsigned short* __restrict__ sval,
                                                  const int* __restrict__ scnt,
                                                  float* __restrict__ avg) {
    __shared__ float accv[1024];
    int tid = threadIdx.x;
    int grow = blockIdx.x;
    for (int i = tid; i < 1024; i += 256) accv[i] = 0.f;
    __syncthreads();
    int h = tid >> 4, sl = tid & 15;
    int n = scnt[grow * H_ + h];
    if (sl < n) {
        size_t base = ((size_t)grow * H_ + h) * 16;
        int idx = sidx[base + sl];
        float v = bf2f(sval[base + sl]);
        atomicAdd(&accv[idx], v);
    }
    __syncthreads();
    float* dst = avg + (size_t)grow * S_;
    for (int i = tid; i < 256; i += 256) {
        float4 o;
        o.x = accv[i * 4 + 0] * 0.0625f;
        o.y = accv[i * 4 + 1] * 0.0625f;
        o.z = accv[i * 4 + 2] * 0.0625f;
        o.w = accv[i * 4 + 3] * 0.0625f;
        *(float4*)(dst + i * 4) = o;
    }
}

extern "C" void kernel_launch(void* const* d_in, const int* in_sizes, int n_in,
                              void* d_out, int out_size, void* d_ws, size_t ws_size,
                              hipStream_t stream) {
    const float* x  = (const float*)d_in[0];
    const float* Wq = (const float*)d_in[1];
    const float* bq = (const float*)d_in[2];
    const float* Wk = (const float*)d_in[3];
    const float* bk = (const float*)d_in[4];
    const float* Wv = (const float*)d_in[5];
    const float* bv = (const float*)d_in[6];
    const float* Wo = (const float*)d_in[7];
    const float* bo = (const float*)d_in[8];

    float* xout = (float*)d_out;                   // (B,S,D)
    float* avg  = xout + (size_t)BS * D_;          // (B,S,S)

    char* ws = (char*)d_ws;
    unsigned short* qhB  = (unsigned short*)(ws + 0);               // 8 MB
    unsigned short* qlB  = (unsigned short*)(ws + (8u << 20));      // 8 MB
    unsigned short* khB  = (unsigned short*)(ws + (16u << 20));     // 8 MB
    unsigned short* klB  = (unsigned short*)(ws + (24u << 20));     // 8 MB
    unsigned short* WqTh = (unsigned short*)(ws + (32u << 20));     // 2 MB
    unsigned short* WqTl = (unsigned short*)(ws + (34u << 20));     // 2 MB
    unsigned short* WkTh = (unsigned short*)(ws + (36u << 20));     // 2 MB
    unsigned short* WkTl = (unsigned short*)(ws + (38u << 20));     // 2 MB
    unsigned short* ochB = WqTh;                                    // alias 32..40 MB (dead after projg)
    unsigned short* WoTh = (unsigned short*)(ws + (40u << 20));     // 2 MB
    unsigned short* WvTh = (unsigned short*)(ws + (42u << 20));     // 256 KB (128x1024 bf16)
    unsigned short* WvTl = (unsigned short*)(ws + (42u << 20) + (256u << 10));  // 256 KB
    float* bvp = (float*)(ws + (42u << 20) + (512u << 10));         // 512 B
    float* vshb = (float*)(ws + (43u << 20));                       // 1 MB
    unsigned short* sidx = (unsigned short*)(ws + (44u << 20));     // 2 MB
    unsigned short* sval = (unsigned short*)(ws + (46u << 20));     // 2 MB
    int* scnt = (int*)(ws + (48u << 20));                           // 256 KB

    prep2<<<3584, 256, 0, stream>>>(Wq, Wk, Wo, Wv, bv, WqTh, WqTl, WkTh, WkTl, WoTh, WvTh, WvTl, bvp);
    projg<<<dim3(17, 32), 256, 0, stream>>>(x, WqTh, WqTl, WkTh, WkTl, WvTh, WvTl,
                                            bq, bk, bvp, qhB, qlB, khB, klB, vshb);
    attn8<<<4096, 256, 0, stream>>>(qhB, qlB, khB, klB, vshb, ochB, sidx, sval, scnt);
    avg_reduce<<<4096, 256, 0, stream>>>(sidx, sval, scnt, avg);
    outg<<<dim3(8, 32), 256, 0, stream>>>(ochB, WoTh, bo, xout);
}